// Round 1
// baseline (44.322 us; speedup 1.0000x reference)
//
#include <hip/hip_runtime.h>
#include <hip/hip_bf16.h>

// Problem constants (from reference)
#define BB   32
#define NN   64
#define CC   3
#define HH   512
#define WW   512
#define PP   16
#define PLANE (HH * WW)          // 262144 floats per channel plane

// One thread per (b, n, i, j): 3 atomic adds (one per channel).
// t layout: j fastest (16), then i (16), then pn = b*N + n.
__global__ __launch_bounds__(256)
void ImagePatch_scatter_kernel(const float* __restrict__ emb,
                               const int*   __restrict__ labels,
                               const int*   __restrict__ top_left,
                               float*       __restrict__ out) {
    int t  = blockIdx.x * blockDim.x + threadIdx.x;   // [0, B*N*P*P)
    int j  = t & (PP - 1);
    int i  = (t >> 4) & (PP - 1);
    int pn = t >> 8;                                  // b*N + n  in [0, B*N)

    int label = labels[pn];
    int r = top_left[pn * 2 + 0] + i;                 // row in [0, H-1]
    int c = top_left[pn * 2 + 1] + j;                 // col in [0, W-1]
    int b = pn >> 6;                                  // / N

    // emb row: [3, P, P] layout -> channel stride P*P
    const float* e = emb + (size_t)label * (CC * PP * PP) + i * PP + j;
    float* o = out + (size_t)b * (CC * PLANE) + (size_t)r * WW + c;

    atomicAdd(o,             e[0]);
    atomicAdd(o + PLANE,     e[PP * PP]);
    atomicAdd(o + 2 * PLANE, e[2 * PP * PP]);
}

extern "C" void kernel_launch(void* const* d_in, const int* in_sizes, int n_in,
                              void* d_out, int out_size, void* d_ws, size_t ws_size,
                              hipStream_t stream) {
    const float* image    = (const float*)d_in[0];   // [B, 3, H, W]
    const float* emb      = (const float*)d_in[1];   // [128, 768]
    const int*   labels   = (const int*)d_in[2];     // [B, N]
    const int*   top_left = (const int*)d_in[3];     // [B, N, 2]
    float*       out      = (float*)d_out;           // [B, 3, H, W]

    // 1) out = image (pure D2D copy, stream-ordered, graph-capture safe)
    size_t bytes = (size_t)BB * CC * HH * WW * sizeof(float);
    hipMemcpyAsync(out, image, bytes, hipMemcpyDeviceToDevice, stream);

    // 2) scatter-add patches (overlaps sum -> atomics)
    int total  = BB * NN * PP * PP;                  // 524288
    int block  = 256;
    int grid   = total / block;                      // 2048
    ImagePatch_scatter_kernel<<<grid, block, 0, stream>>>(emb, labels, top_left, out);
}

// Round 2
// 36.525 us; speedup vs baseline: 1.2135x; 1.2135x over previous
//
#include <hip/hip_runtime.h>
#include <hip/hip_bf16.h>

// Problem constants (from reference)
#define B_   32
#define N_   64
#define C_   3
#define H_   512
#define W_   512
#define P_   16
#define PLANE (H_ * W_)          // 262144 floats per channel plane
#define IMG   (C_ * PLANE)       // 786432 floats per batch image

// One block = one output row (b, r), all 3 channels.
// 128 threads x float4 = 512 columns = full row width.
// Wave 0 builds the list of patches of image b overlapping row r (expected ~2),
// then every thread gathers: out = image + sum(overlapping patch values).
// Pure gather -> no atomics, no second pass, overlaps sum naturally.
__global__ __launch_bounds__(128)
void ImagePatch_fused_kernel(const float* __restrict__ image,
                             const float* __restrict__ emb,
                             const int*   __restrict__ labels,
                             const int*   __restrict__ top_left,
                             float*       __restrict__ out) {
    __shared__ int s_cnt;
    __shared__ int s_dr[N_];   // r - tr        in [0,16)
    __shared__ int s_tc[N_];   // patch left col
    __shared__ int s_lb[N_];   // label

    const int bid = blockIdx.x;
    const int r   = bid & (H_ - 1);
    const int b   = bid >> 9;          // / H_
    const int tid = threadIdx.x;

    // ---- build overlap list (first wave only; all 64 lanes active) ----
    if (tid < 64) {
        const int idx = b * N_ + tid;
        const int tr  = top_left[idx * 2];
        const unsigned dr = (unsigned)(r - tr);
        const bool cover  = dr < P_;
        const unsigned long long m = __ballot(cover);
        if (cover) {
            const int pos = __popcll(m & ((1ull << tid) - 1ull));
            s_dr[pos] = (int)dr;
            s_tc[pos] = top_left[idx * 2 + 1];
            s_lb[pos] = labels[idx];
        }
        if (tid == 0) s_cnt = __popcll(m);
    }
    __syncthreads();

    // ---- streaming copy + gather-add ----
    const int c0 = tid * 4;
    const size_t base = (size_t)b * IMG + (size_t)r * W_ + c0;

    float4 v0 = *(const float4*)(image + base);
    float4 v1 = *(const float4*)(image + base + PLANE);
    float4 v2 = *(const float4*)(image + base + 2 * PLANE);

    const int cnt = s_cnt;
    for (int k = 0; k < cnt; ++k) {
        const int tc = s_tc[k];
        // does [c0, c0+4) intersect [tc, tc+16) ?
        if (c0 + 3 >= tc && c0 < tc + P_) {
            const float* e = emb + s_lb[k] * (C_ * P_ * P_) + s_dr[k] * P_;
            #pragma unroll
            for (int q = 0; q < 4; ++q) {
                const unsigned dc = (unsigned)(c0 + q - tc);
                if (dc < P_) {
                    ((float*)&v0)[q] += e[dc];                 // ch 0
                    ((float*)&v1)[q] += e[P_ * P_ + dc];       // ch 1
                    ((float*)&v2)[q] += e[2 * P_ * P_ + dc];   // ch 2
                }
            }
        }
    }

    *(float4*)(out + base)             = v0;
    *(float4*)(out + base + PLANE)     = v1;
    *(float4*)(out + base + 2 * PLANE) = v2;
}

extern "C" void kernel_launch(void* const* d_in, const int* in_sizes, int n_in,
                              void* d_out, int out_size, void* d_ws, size_t ws_size,
                              hipStream_t stream) {
    const float* image    = (const float*)d_in[0];   // [B, 3, H, W]
    const float* emb      = (const float*)d_in[1];   // [128, 768]
    const int*   labels   = (const int*)d_in[2];     // [B, N]
    const int*   top_left = (const int*)d_in[3];     // [B, N, 2]
    float*       out      = (float*)d_out;           // [B, 3, H, W]

    const int grid = B_ * H_;                        // 16384 blocks, one per row
    ImagePatch_fused_kernel<<<grid, 128, 0, stream>>>(image, emb, labels, top_left, out);
}